// Round 7
// baseline (772.731 us; speedup 1.0000x reference)
//
#include <hip/hip_runtime.h>

#define NN 100000
#define EE 1600000
#define DD 128
#define TD 640
#define EPSV 1e-5f
#define NBLK_SCAN 391   // ceil(NN/256)
#define SB 1024         // stats partial blocks
#define NRANGE 8        // XCD count; node range slice = NN/8
#define RSZ 12500       // NN / NRANGE
#define NCHUNK 256      // edge chunks
#define CSZ 6250        // EE / NCHUNK
#define FB 32           // nodes per fused block; NN/FB = 3125 exactly

typedef __attribute__((ext_vector_type(8))) short bf16x8;
typedef __attribute__((ext_vector_type(4))) float f32x4;

__device__ inline unsigned short f2b(float f) {
  union { float f; unsigned u; } x; x.f = f;
  unsigned r = x.u + 0x7fff + ((x.u >> 16) & 1);
  return (unsigned short)(r >> 16);
}
__device__ inline float b2f(unsigned short u) {
  union { unsigned u; float f; } x; x.u = ((unsigned)u) << 16;
  return x.f;
}

// ---------- BN stats, stage 1 (fp32 input)
__global__ __launch_bounds__(256) void k_stats_partial(const float* __restrict__ x,
    float* __restrict__ ps, float* __restrict__ pq) {
  float s0=0.f,s1=0.f,s2=0.f,s3=0.f,q0=0.f,q1=0.f,q2=0.f,q3=0.f;
  const float4* x4 = reinterpret_cast<const float4*>(x);
  const int total = NN * DD / 4;
  for (int i = blockIdx.x * 256 + threadIdx.x; i < total; i += SB * 256) {
    float4 v = x4[i];
    s0 += v.x; s1 += v.y; s2 += v.z; s3 += v.w;
    q0 += v.x*v.x; q1 += v.y*v.y; q2 += v.z*v.z; q3 += v.w*v.w;
  }
  __shared__ float ls[256], lq[256];
  int t = threadIdx.x;
  float sv[4] = {s0,s1,s2,s3}, qv[4] = {q0,q1,q2,q3};
#pragma unroll
  for (int j = 0; j < 4; ++j) {
    ls[t] = sv[j]; lq[t] = qv[j];
    __syncthreads();
    if (t < 32) {
      float a = 0.f, b = 0.f;
#pragma unroll
      for (int k = 0; k < 8; ++k) { a += ls[t + 32*k]; b += lq[t + 32*k]; }
      ps[blockIdx.x * DD + t*4 + j] = a;
      pq[blockIdx.x * DD + t*4 + j] = b;
    }
    __syncthreads();
  }
}

// ---------- BN stats, stage 1 (bf16 input)
__global__ __launch_bounds__(256) void k_stats_partial_bf(const unsigned short* __restrict__ x,
    float* __restrict__ ps, float* __restrict__ pq) {
  float s0=0.f,s1=0.f,s2=0.f,s3=0.f,q0=0.f,q1=0.f,q2=0.f,q3=0.f;
  const ushort4* x4 = reinterpret_cast<const ushort4*>(x);
  const int total = NN * DD / 4;
  for (int i = blockIdx.x * 256 + threadIdx.x; i < total; i += SB * 256) {
    ushort4 u = x4[i];
    float vx = b2f(u.x), vy = b2f(u.y), vz = b2f(u.z), vw = b2f(u.w);
    s0 += vx; s1 += vy; s2 += vz; s3 += vw;
    q0 += vx*vx; q1 += vy*vy; q2 += vz*vz; q3 += vw*vw;
  }
  __shared__ float ls[256], lq[256];
  int t = threadIdx.x;
  float sv[4] = {s0,s1,s2,s3}, qv[4] = {q0,q1,q2,q3};
#pragma unroll
  for (int j = 0; j < 4; ++j) {
    ls[t] = sv[j]; lq[t] = qv[j];
    __syncthreads();
    if (t < 32) {
      float a = 0.f, b = 0.f;
#pragma unroll
      for (int k = 0; k < 8; ++k) { a += ls[t + 32*k]; b += lq[t + 32*k]; }
      ps[blockIdx.x * DD + t*4 + j] = a;
      pq[blockIdx.x * DD + t*4 + j] = b;
    }
    __syncthreads();
  }
}

// ---------- BN stats, stage 2
__global__ __launch_bounds__(1024) void k_stats_final(const float* __restrict__ ps,
    const float* __restrict__ pq, const float* __restrict__ g,
    const float* __restrict__ be, float* __restrict__ ssb) {
  __shared__ float ls[1024], lq[1024];
  int t = threadIdx.x;
  int col = t & 127, seg = t >> 7;
  float s = 0.f, q = 0.f;
  for (int b = seg; b < SB; b += 8) { s += ps[b * DD + col]; q += pq[b * DD + col]; }
  ls[t] = s; lq[t] = q;
  __syncthreads();
  if (t < 128) {
#pragma unroll
    for (int k = 1; k < 8; ++k) { s += ls[t + 128*k]; q += lq[t + 128*k]; }
    float mean = s * (1.0f / NN);
    float var  = q * (1.0f / NN) - mean * mean;
    float sc = g[t] * rsqrtf(var + EPSV);
    ssb[t] = sc;
    ssb[DD + t] = be[t] - mean * sc;
  }
}

// ---------- fused BN+ReLU+bf16 cast (fp32 input)
__global__ __launch_bounds__(256) void k_act(const float* __restrict__ x,
    const float* __restrict__ ss, unsigned short* __restrict__ A) {
  int i = blockIdx.x * 256 + threadIdx.x;  // [0, NN*DD/4) exactly
  float4 v = reinterpret_cast<const float4*>(x)[i];
  int c4 = (i & 31) * 4;
  float s0 = ss[c4+0], s1 = ss[c4+1], s2 = ss[c4+2], s3 = ss[c4+3];
  float h0 = ss[DD+c4+0], h1 = ss[DD+c4+1], h2 = ss[DD+c4+2], h3 = ss[DD+c4+3];
  ushort4 o;
  o.x = f2b(fmaxf(0.f, v.x * s0 + h0));
  o.y = f2b(fmaxf(0.f, v.y * s1 + h1));
  o.z = f2b(fmaxf(0.f, v.z * s2 + h2));
  o.w = f2b(fmaxf(0.f, v.w * s3 + h3));
  reinterpret_cast<ushort4*>(A)[i] = o;
}

// ---------- fused BN+ReLU+bf16 cast (bf16 input)
__global__ __launch_bounds__(256) void k_act_bf(const unsigned short* __restrict__ x,
    const float* __restrict__ ss, unsigned short* __restrict__ A) {
  int i = blockIdx.x * 256 + threadIdx.x;
  ushort4 u = reinterpret_cast<const ushort4*>(x)[i];
  int c4 = (i & 31) * 4;
  float s0 = ss[c4+0], s1 = ss[c4+1], s2 = ss[c4+2], s3 = ss[c4+3];
  float h0 = ss[DD+c4+0], h1 = ss[DD+c4+1], h2 = ss[DD+c4+2], h3 = ss[DD+c4+3];
  ushort4 o;
  o.x = f2b(fmaxf(0.f, b2f(u.x) * s0 + h0));
  o.y = f2b(fmaxf(0.f, b2f(u.y) * s1 + h1));
  o.z = f2b(fmaxf(0.f, b2f(u.z) * s2 + h2));
  o.w = f2b(fmaxf(0.f, b2f(u.w) * s3 + h3));
  reinterpret_cast<ushort4*>(A)[i] = o;
}

// ---------- W -> B2 rearrange + bf16: B2[d][t*128+k] = W[(t*128+d)*128+k]
__global__ void k_cvt_b2(const float* __restrict__ w, unsigned short* __restrict__ o) {
  int i = blockIdx.x * 256 + threadIdx.x;  // [0, 20480)
  int tt = i >> 12;
  int rem = i & 4095;
  int d = rem >> 5, j = rem & 31;
  float4 v = reinterpret_cast<const float4*>(w)[i];
  ushort4 u; u.x = f2b(v.x); u.y = f2b(v.y); u.z = f2b(v.z); u.w = f2b(v.w);
  reinterpret_cast<ushort4*>(o)[d * 160 + tt * 32 + j] = u;
}

// ---------- CSR build
__global__ void k_zero(int* p, int n) {
  int i = blockIdx.x * 256 + threadIdx.x;
  if (i < n) p[i] = 0;
}
__global__ __launch_bounds__(256) void k_hist(const int* __restrict__ dst,
    int* __restrict__ cnt) {
  const int range = blockIdx.x & (NRANGE - 1);
  const int chunk = blockIdx.x >> 3;
  const int lo = range * RSZ;
  const int base = chunk * CSZ;
  for (int i = base + threadIdx.x; i < base + CSZ; i += 256) {
    int d = dst[i];
    if ((unsigned)(d - lo) < RSZ) atomicAdd(&cnt[d], 1);
  }
}
__global__ __launch_bounds__(256) void k_scan_blk(const int* __restrict__ cnt, int* __restrict__ bsum) {
  __shared__ int sh[256];
  int idx = blockIdx.x * 256 + threadIdx.x;
  sh[threadIdx.x] = (idx < NN) ? cnt[idx] : 0;
  __syncthreads();
  for (int off = 128; off > 0; off >>= 1) {
    if (threadIdx.x < off) sh[threadIdx.x] += sh[threadIdx.x + off];
    __syncthreads();
  }
  if (threadIdx.x == 0) bsum[blockIdx.x] = sh[0];
}
__global__ __launch_bounds__(512) void k_scan_top(int* __restrict__ bsum) {
  __shared__ int sh[512];
  int t = threadIdx.x;
  int v = (t < NBLK_SCAN) ? bsum[t] : 0;
  sh[t] = v;
  __syncthreads();
  for (int off = 1; off < 512; off <<= 1) {
    int add = (t >= off) ? sh[t - off] : 0;
    __syncthreads();
    sh[t] += add;
    __syncthreads();
  }
  if (t < NBLK_SCAN) bsum[t] = sh[t] - v;  // exclusive
}
__global__ __launch_bounds__(256) void k_scan_fin(const int* __restrict__ cnt,
    const int* __restrict__ bsum, int* __restrict__ row_ptr, int* __restrict__ cursor) {
  __shared__ int sh[256];
  int idx = blockIdx.x * 256 + threadIdx.x;
  int v = (idx < NN) ? cnt[idx] : 0;
  sh[threadIdx.x] = v;
  __syncthreads();
  for (int off = 1; off < 256; off <<= 1) {
    int add = (threadIdx.x >= off) ? sh[threadIdx.x - off] : 0;
    __syncthreads();
    sh[threadIdx.x] += add;
    __syncthreads();
  }
  int excl = bsum[blockIdx.x] + sh[threadIdx.x] - v;
  if (idx < NN) { row_ptr[idx] = excl; cursor[idx] = excl; }
  if (idx == NN - 1) row_ptr[NN] = excl + v;
}
__global__ __launch_bounds__(256) void k_scatter(const int* __restrict__ src,
    const int* __restrict__ dst, const int* __restrict__ et,
    int* __restrict__ cursor, int* __restrict__ payload) {
  const int range = blockIdx.x & (NRANGE - 1);
  const int chunk = blockIdx.x >> 3;
  const int lo = range * RSZ;
  const int base = chunk * CSZ;
  for (int i = base + threadIdx.x; i < base + CSZ; i += 256) {
    int d = dst[i];
    if ((unsigned)(d - lo) < RSZ) {
      int pos = atomicAdd(&cursor[d], 1);
      payload[pos] = (src[i] << 3) | et[i];
    }
  }
}

// ---------- FUSED: per-dst type-aggregate (regs) -> swizzled LDS tile -> MFMA GEMM
// y[n,d] = sum_t Gacc[n, t*128:] . B2[d, t*128:] + sum_t cnt[n][t]*b[t*128+d] (+ base)
// RND=0: bf16 out (y1). RND=1: fp32 out + base (d_out).
template<int RND>
__global__ __launch_bounds__(512, 4) void k_fused(const unsigned short* __restrict__ Ab,
    const int* __restrict__ rp, const int* __restrict__ pl,
    const unsigned short* __restrict__ B2, const float* __restrict__ bias,
    const float* __restrict__ base, void* __restrict__ out) {
  __shared__ __align__(16) unsigned short gl[FB * TD];  // 40 KB bf16, XOR-swizzled rows
  __shared__ int lcnt[FB][8];                            // 1 KB
  const int t = threadIdx.x;
  const int l = t & 63;
  const int w = t >> 6;        // 0..7
  const int node0 = blockIdx.x * FB;
  char* glc = reinterpret_cast<char*>(gl);

  // ---- edge phase: wave w owns local rows w*4 .. w*4+3 (register accumulation)
#pragma unroll 1
  for (int i = 0; i < 4; ++i) {
    const int nn = w * 4 + i;
    const int n = node0 + nn;
    const int s = rp[n], e = rp[n + 1];
    float a00=0.f,a01=0.f,a10=0.f,a11=0.f,a20=0.f,a21=0.f,a30=0.f,a31=0.f,a40=0.f,a41=0.f;
    int c0=0,c1=0,c2=0,c3=0,c4=0;
    int j = s;
    for (; j + 1 < e; j += 2) {
      int p0 = pl[j], p1 = pl[j + 1];
      ushort2 u0 = *reinterpret_cast<const ushort2*>(Ab + (p0 >> 3) * DD + 2 * l);
      ushort2 u1 = *reinterpret_cast<const ushort2*>(Ab + (p1 >> 3) * DD + 2 * l);
      float x0 = b2f(u0.x), x1 = b2f(u0.y);
      switch (p0 & 7) {
        case 0: a00 += x0; a01 += x1; c0++; break;
        case 1: a10 += x0; a11 += x1; c1++; break;
        case 2: a20 += x0; a21 += x1; c2++; break;
        case 3: a30 += x0; a31 += x1; c3++; break;
        default: a40 += x0; a41 += x1; c4++; break;
      }
      float z0 = b2f(u1.x), z1 = b2f(u1.y);
      switch (p1 & 7) {
        case 0: a00 += z0; a01 += z1; c0++; break;
        case 1: a10 += z0; a11 += z1; c1++; break;
        case 2: a20 += z0; a21 += z1; c2++; break;
        case 3: a30 += z0; a31 += z1; c3++; break;
        default: a40 += z0; a41 += z1; c4++; break;
      }
    }
    if (j < e) {
      int p0 = pl[j];
      ushort2 u0 = *reinterpret_cast<const ushort2*>(Ab + (p0 >> 3) * DD + 2 * l);
      float x0 = b2f(u0.x), x1 = b2f(u0.y);
      switch (p0 & 7) {
        case 0: a00 += x0; a01 += x1; c0++; break;
        case 1: a10 += x0; a11 += x1; c1++; break;
        case 2: a20 += x0; a21 += x1; c2++; break;
        case 3: a30 += x0; a31 += x1; c3++; break;
        default: a40 += x0; a41 += x1; c4++; break;
      }
    }
    // write the node's 640-row once to LDS (bf16, swizzled). Each byte written
    // exactly once across the block -> no zero-init needed.
    const unsigned rowbase = nn * (TD * 2);
    const unsigned swz = (unsigned)((nn & 7) << 4);
    ushort2 o;
    o.x = f2b(a00); o.y = f2b(a01);
    *reinterpret_cast<ushort2*>(glc + ((rowbase + 0*256 + 4*l) ^ swz)) = o;
    o.x = f2b(a10); o.y = f2b(a11);
    *reinterpret_cast<ushort2*>(glc + ((rowbase + 1*256 + 4*l) ^ swz)) = o;
    o.x = f2b(a20); o.y = f2b(a21);
    *reinterpret_cast<ushort2*>(glc + ((rowbase + 2*256 + 4*l) ^ swz)) = o;
    o.x = f2b(a30); o.y = f2b(a31);
    *reinterpret_cast<ushort2*>(glc + ((rowbase + 3*256 + 4*l) ^ swz)) = o;
    o.x = f2b(a40); o.y = f2b(a41);
    *reinterpret_cast<ushort2*>(glc + ((rowbase + 4*256 + 4*l) ^ swz)) = o;
    if (l < 5) lcnt[nn][l] = (l == 0) ? c0 : (l == 1) ? c1 : (l == 2) ? c2 : (l == 3) ? c3 : c4;
  }
  __syncthreads();

  // ---- GEMM phase: wave computes rows rh*16..+15 x cols wc..wc+31, K=640
  const int rh = w >> 2;          // 0/1
  const int wc = (w & 3) * 32;
  const int lm = l & 15, hi = l >> 4;
  const int rr = rh * 16 + lm;    // A-row this lane reads
  const unsigned abase = (unsigned)(rr * (TD * 2));
  const unsigned aswz = (unsigned)((rr & 7) << 4);
  const unsigned short* bp0 = B2 + (wc + lm) * TD;
  const unsigned short* bp1 = B2 + (wc + 16 + lm) * TD;
  f32x4 acc0 = {}, acc1 = {};
#pragma unroll 4
  for (int kk = 0; kk < 20; ++kk) {
    bf16x8 af = *reinterpret_cast<const bf16x8*>(glc + ((abase + kk*64 + hi*16) ^ aswz));
    bf16x8 b0 = *reinterpret_cast<const bf16x8*>(bp0 + kk*32 + hi*8);
    bf16x8 b1 = *reinterpret_cast<const bf16x8*>(bp1 + kk*32 + hi*8);
    acc0 = __builtin_amdgcn_mfma_f32_16x16x32_bf16(af, b0, acc0, 0, 0, 0);
    acc1 = __builtin_amdgcn_mfma_f32_16x16x32_bf16(af, b1, acc1, 0, 0, 0);
  }

  // epilogue: + sum_t cnt*b (+ base); lane owns cols {wc+lm, wc+16+lm}, rows rh*16+hi*4+r
  const int col0 = wc + lm, col1 = wc + 16 + lm;
  float b00 = bias[col0], b01 = bias[128+col0], b02 = bias[256+col0],
        b03 = bias[384+col0], b04 = bias[512+col0];
  float b10 = bias[col1], b11 = bias[128+col1], b12 = bias[256+col1],
        b13 = bias[384+col1], b14 = bias[512+col1];
#pragma unroll
  for (int r = 0; r < 4; ++r) {
    int row = rh * 16 + hi * 4 + r;
    int g = node0 + row;  // always < NN (NN % FB == 0)
    float c0 = (float)lcnt[row][0], c1 = (float)lcnt[row][1], c2 = (float)lcnt[row][2],
          c3 = (float)lcnt[row][3], c4 = (float)lcnt[row][4];
    float v0 = acc0[r] + c0*b00 + c1*b01 + c2*b02 + c3*b03 + c4*b04;
    float v1 = acc1[r] + c0*b10 + c1*b11 + c2*b12 + c3*b13 + c4*b14;
    if (RND == 1) {
      v0 += base[g * DD + col0];
      v1 += base[g * DD + col1];
      reinterpret_cast<float*>(out)[g * DD + col0] = v0;
      reinterpret_cast<float*>(out)[g * DD + col1] = v1;
    } else {
      reinterpret_cast<unsigned short*>(out)[g * DD + col0] = f2b(v0);
      reinterpret_cast<unsigned short*>(out)[g * DD + col1] = f2b(v1);
    }
  }
}

extern "C" void kernel_launch(void* const* d_in, const int* in_sizes, int n_in,
                              void* d_out, int out_size, void* d_ws, size_t ws_size,
                              hipStream_t stream) {
  const float* features = (const float*)d_in[0];
  const int*   src   = (const int*)d_in[1];
  const int*   dst   = (const int*)d_in[2];
  const int*   etype = (const int*)d_in[3];
  const float* w1  = (const float*)d_in[4];
  const float* b1  = (const float*)d_in[5];
  const float* g1  = (const float*)d_in[6];
  const float* be1 = (const float*)d_in[7];
  const float* w2  = (const float*)d_in[8];
  const float* b2  = (const float*)d_in[9];
  const float* g2  = (const float*)d_in[10];
  const float* be2 = (const float*)d_in[11];

  char* ws = (char*)d_ws;
  unsigned short* Ab   = (unsigned short*)(ws + 0);            // 25,600,000 B
  float*          ps   = (float*)(ws + 0);                     // aliases Ab (dead before k_act)
  float*          pq   = (float*)(ws + 524288);
  unsigned short* y1   = (unsigned short*)(ws + 25600000);     // 25,600,000 B (bf16)
  unsigned short* b2a  = (unsigned short*)(ws + 51200000);     // 163,840 B
  unsigned short* b2b  = (unsigned short*)(ws + 51363840);     // 163,840 B
  float*          ssb  = (float*)(ws + 51527680);              // 1,024 B
  int*            rowp = (int*)(ws + 51528704);                // 400,016 B
  int*            curs = (int*)(ws + 51928720);                // 400,000 B
  int*            payl = (int*)(ws + 52328720);                // 6,400,000 B
  int*            bsum = (int*)(ws + 58728720);                // 2,048 B
  // total: 58,730,768 B

  // CSR build (shared by both rounds)
  k_zero<<<(NN + 255) / 256, 256, 0, stream>>>(curs, NN);
  k_hist<<<NRANGE * NCHUNK, 256, 0, stream>>>(dst, curs);
  k_scan_blk<<<NBLK_SCAN, 256, 0, stream>>>(curs, bsum);
  k_scan_top<<<1, 512, 0, stream>>>(bsum);
  k_scan_fin<<<NBLK_SCAN, 256, 0, stream>>>(curs, bsum, rowp, curs);
  k_scatter<<<NRANGE * NCHUNK, 256, 0, stream>>>(src, dst, etype, curs, payl);

  // weights -> rearranged bf16 B2
  k_cvt_b2<<<80, 256, 0, stream>>>(w1, b2a);
  k_cvt_b2<<<80, 256, 0, stream>>>(w2, b2b);

  // ---- round 1
  k_stats_partial<<<SB, 256, 0, stream>>>(features, ps, pq);
  k_stats_final<<<1, 1024, 0, stream>>>(ps, pq, g1, be1, ssb);
  k_act<<<12500, 256, 0, stream>>>(features, ssb, Ab);
  k_fused<0><<<NN / FB, 512, 0, stream>>>(Ab, rowp, payl, b2a, b1, nullptr, y1);

  // ---- round 2
  k_stats_partial_bf<<<SB, 256, 0, stream>>>(y1, ps, pq);
  k_stats_final<<<1, 1024, 0, stream>>>(ps, pq, g2, be2, ssb);
  k_act_bf<<<12500, 256, 0, stream>>>(y1, ssb, Ab);
  k_fused<1><<<NN / FB, 512, 0, stream>>>(Ab, rowp, payl, b2b, b2, features, d_out);
}